// Round 1
// baseline (558.535 us; speedup 1.0000x reference)
//
#include <hip/hip_runtime.h>

#define BB   8
#define TT   1024
#define NCBN 2
#define DD   128
#define KK   8192

constexpr int OUT_IDX_OFF  = BB * 256 * TT;               // 2097152
constexpr int OUT_LOSS_OFF = OUT_IDX_OFF + BB * NCBN * TT; // 2113536

// ---------------------------------------------------------------------------
// Kernel 1: c2[n][k] = sum_d codebooks[n][k][d]^2   (2*8192 entries)
// ---------------------------------------------------------------------------
__global__ __launch_bounds__(256)
void c2_kernel(const float* __restrict__ cb, float* __restrict__ c2) {
    int g = blockIdx.x * 256 + threadIdx.x;   // 0..16383  (n*K + k)
    const float4* row = (const float4*)(cb + (size_t)g * DD);
    float s = 0.f;
#pragma unroll
    for (int i = 0; i < DD / 4; ++i) {
        float4 v = row[i];
        s = fmaf(v.x, v.x, s);
        s = fmaf(v.y, v.y, s);
        s = fmaf(v.z, v.z, s);
        s = fmaf(v.w, v.w, s);
    }
    c2[g] = s;
}

// ---------------------------------------------------------------------------
// Kernel 2: distances + argmin.
// grid (128, 2): blockIdx.x = m-tile (64 queries within one b), blockIdx.y = n
// block 512 threads: tx = tid&15 -> 4 queries each, ty = tid>>4 -> 4 codes each
// ---------------------------------------------------------------------------
__global__ __launch_bounds__(512)
void vq_kernel(const float* __restrict__ x, const float* __restrict__ cb,
               const float* __restrict__ c2, int* __restrict__ idx_ws,
               float* __restrict__ out) {
    constexpr int BM = 64, BN = 128;
    __shared__ float Qs[DD][BM];        // [d][m] transposed: 32 KB
    __shared__ float Cs[BN][DD + 4];    // [k][d] natural, +4 pad: 66 KB
    __shared__ float C2s[BN];
    __shared__ float X2s[BM];
    __shared__ float RedV[BM][32];
    __shared__ int   RedI[BM][32];

    const int tid = threadIdx.x;
    const int mt  = blockIdx.x;          // 0..127
    const int n   = blockIdx.y;          // 0..1
    const int b   = mt >> 4;             // 16 tiles of 64 per b (T=1024)
    const int t0  = (mt & 15) * BM;
    const int tx  = tid & 15;
    const int ty  = tid >> 4;            // 0..31

    // ---- stage Q tile (transposed into LDS): x[(b*256 + n*128 + d)*1024 + t]
    for (int i = tid; i < DD * (BM / 4); i += 512) {
        int d  = i >> 4;
        int mg = (i & 15) * 4;
        float4 v = *(const float4*)(x + ((size_t)(b * 256 + n * 128 + d)) * TT + t0 + mg);
        *(float4*)&Qs[d][mg] = v;
    }
    __syncthreads();

    // ---- x2 per query (match reference: d2 = (x2 - 2*xc) + c2)
    if (tid < BM) {
        float s = 0.f;
        for (int d = 0; d < DD; ++d) { float v = Qs[d][tid]; s = fmaf(v, v, s); }
        X2s[tid] = s;
    }
    __syncthreads();

    float x2r[4];
#pragma unroll
    for (int i = 0; i < 4; ++i) x2r[i] = X2s[tx * 4 + i];

    float bestv[4] = {3.4e38f, 3.4e38f, 3.4e38f, 3.4e38f};
    int   besti[4] = {0, 0, 0, 0};

    for (int k0 = 0; k0 < KK; k0 += BN) {
        __syncthreads();
        // stage code chunk: coalesced global float4, 4-way-conflict LDS store (cold)
        for (int i = tid; i < BN * (DD / 4); i += 512) {
            int kn = i >> 5;
            int dq = (i & 31) * 4;
            float4 v = *(const float4*)(cb + ((size_t)n * KK + k0 + kn) * DD + dq);
            *(float4*)&Cs[kn][dq] = v;
        }
        if (tid < BN / 4)
            *(float4*)&C2s[tid * 4] = *(const float4*)(c2 + n * KK + k0 + tid * 4);
        __syncthreads();

        float acc[4][4] = {};
#pragma unroll 8
        for (int d4 = 0; d4 < DD; d4 += 4) {
            float a[4][4];   // [dd][i]  (4 queries at depth d4+dd)
            float bv[4][4];  // [j][dd]  (code j, 4 depths)
#pragma unroll
            for (int dd = 0; dd < 4; ++dd) {
                float4 v = *(const float4*)&Qs[d4 + dd][tx * 4];
                a[dd][0] = v.x; a[dd][1] = v.y; a[dd][2] = v.z; a[dd][3] = v.w;
            }
#pragma unroll
            for (int j = 0; j < 4; ++j) {
                float4 v = *(const float4*)&Cs[ty * 4 + j][d4];
                bv[j][0] = v.x; bv[j][1] = v.y; bv[j][2] = v.z; bv[j][3] = v.w;
            }
#pragma unroll
            for (int i = 0; i < 4; ++i)
#pragma unroll
                for (int j = 0; j < 4; ++j)
#pragma unroll
                    for (int dd = 0; dd < 4; ++dd)
                        acc[i][j] = fmaf(a[dd][i], bv[j][dd], acc[i][j]);
        }

        // score + running argmin (k strictly ascending per thread -> '<' keeps
        // first occurrence, matching jnp.argmin)
#pragma unroll
        for (int j = 0; j < 4; ++j) {
            float cc = C2s[ty * 4 + j];
            int   kk = k0 + ty * 4 + j;
#pragma unroll
            for (int i = 0; i < 4; ++i) {
                float u = x2r[i] - 2.0f * acc[i][j];
                float s = u + cc;
                if (s < bestv[i]) { bestv[i] = s; besti[i] = kk; }
            }
        }
    }

    __syncthreads();
#pragma unroll
    for (int i = 0; i < 4; ++i) {
        RedV[tx * 4 + i][ty] = bestv[i];
        RedI[tx * 4 + i][ty] = besti[i];
    }
    __syncthreads();

    if (tid < BM) {
        int m = tid;
        float bv = RedV[m][0];
        int   bi = RedI[m][0];
#pragma unroll
        for (int p = 1; p < 32; ++p) {
            float v  = RedV[m][p];
            int   ii = RedI[m][p];
            if (v < bv || (v == bv && ii < bi)) { bv = v; bi = ii; }
        }
        int q = (b * NCBN + n) * TT + t0 + m;
        idx_ws[q] = bi;
        out[OUT_IDX_OFF + q] = (float)bi;   // indices output (as f32 value)
    }
}

// ---------------------------------------------------------------------------
// Kernel 3: gather quantized rows + commitment loss.
// thread per (b, n, t): 16384 threads. Writes coalesced across t per d-slice.
// ---------------------------------------------------------------------------
__global__ __launch_bounds__(256)
void gather_kernel(const float* __restrict__ x, const float* __restrict__ cb,
                   const int* __restrict__ idx_ws, float* __restrict__ out) {
    int g  = blockIdx.x * 256 + threadIdx.x;  // 0..16383
    int t  = g & (TT - 1);
    int nn = (g >> 10) & (NCBN - 1);
    int b  = g >> 11;

    int k = idx_ws[(b * NCBN + nn) * TT + t];
    const float* crow  = cb + ((size_t)nn * KK + k) * DD;
    const float* xbase = x   + ((size_t)(b * 256 + nn * 128)) * TT + t;
    float*       obase = out + ((size_t)(b * 256 + nn * 128)) * TT + t;

    float lsum = 0.f;
#pragma unroll 4
    for (int d = 0; d < DD; d += 4) {
        float4 q = *(const float4*)(crow + d);
        float qv[4] = {q.x, q.y, q.z, q.w};
#pragma unroll
        for (int u = 0; u < 4; ++u) {
            size_t off = (size_t)(d + u) * TT;
            float xv = xbase[off];
            obase[off] = qv[u];
            float df = xv - qv[u];
            lsum = fmaf(df, df, lsum);
        }
    }

    // block reduce -> one atomic per block
#pragma unroll
    for (int o = 32; o > 0; o >>= 1) lsum += __shfl_down(lsum, o, 64);
    __shared__ float wsum[4];
    int lane = threadIdx.x & 63, w = threadIdx.x >> 6;
    if (lane == 0) wsum[w] = lsum;
    __syncthreads();
    if (threadIdx.x == 0) {
        float tot = wsum[0] + wsum[1] + wsum[2] + wsum[3];
        // loss = 0.25 * sum_n mean_{(B*T),d} = 0.25/2^20 * total = 2^-22 * total
        atomicAdd(out + OUT_LOSS_OFF, tot * 2.384185791015625e-7f);
    }
}

// ---------------------------------------------------------------------------
extern "C" void kernel_launch(void* const* d_in, const int* in_sizes, int n_in,
                              void* d_out, int out_size, void* d_ws, size_t ws_size,
                              hipStream_t stream) {
    (void)in_sizes; (void)n_in; (void)out_size; (void)ws_size;
    const float* x  = (const float*)d_in[0];
    const float* cb = (const float*)d_in[1];
    float* out = (float*)d_out;

    float* c2     = (float*)d_ws;                                  // 16384 f32
    int*   idx_ws = (int*)((char*)d_ws + (size_t)NCBN * KK * 4);   // 16384 i32

    c2_kernel<<<dim3(NCBN * KK / 256), 256, 0, stream>>>(cb, c2);
    hipMemsetAsync((char*)d_out + (size_t)OUT_LOSS_OFF * 4, 0, 4, stream);
    vq_kernel<<<dim3(128, 2), 512, 0, stream>>>(x, cb, c2, idx_ws, out);
    gather_kernel<<<dim3(64), 256, 0, stream>>>(x, cb, idx_ws, out);
}

// Round 2
// 274.725 us; speedup vs baseline: 2.0331x; 2.0331x over previous
//
#include <hip/hip_runtime.h>
#include <hip/hip_bf16.h>

#define BB   8
#define TT   1024
#define NCBN 2
#define DD   128
#define KK   8192
#define MM   8192          // B*T queries per codebook

constexpr int OUT_IDX_OFF  = BB * 256 * TT;                // 2097152
constexpr int OUT_LOSS_OFF = OUT_IDX_OFF + BB * NCBN * TT; // 2113536

#define THR   0.45f        // >= 2*worst-case |y_bf16 - y_f32| (bound ~0.34)
#define QCAP  768

typedef __attribute__((ext_vector_type(8))) short   short8;   // 8 bf16
typedef __attribute__((ext_vector_type(4))) float   float4v;

__device__ __forceinline__ unsigned short f2bf(float v) {
    unsigned u = __float_as_uint(v);
    return (unsigned short)((u + 0x7FFFu + ((u >> 16) & 1u)) >> 16);  // RNE
}

// ---------------------------------------------------------------------------
// Pack x -> Xbf[n][m][d] bf16 (row 256 B), x2[n][m] fp32 (ascending-d fmaf,
// same association as the R1 passing kernel).
// ---------------------------------------------------------------------------
__global__ __launch_bounds__(256)
void pack_x_kernel(const float* __restrict__ x, unsigned short* __restrict__ xbf,
                   float* __restrict__ x2) {
    int g = blockIdx.x * 256 + threadIdx.x;   // n*8192 + m
    int n = g >> 13, m = g & (MM - 1);
    int b = m >> 10, t = m & (TT - 1);
    const float* xp = x + ((size_t)(b * 256 + n * 128)) * TT + t;
    unsigned short* orow = xbf + (size_t)g * DD;
    float s = 0.f;
    for (int d8 = 0; d8 < DD; d8 += 8) {
        unsigned short u[8];
#pragma unroll
        for (int j = 0; j < 8; ++j) {
            float v = xp[(size_t)(d8 + j) * TT];
            s = fmaf(v, v, s);
            u[j] = f2bf(v);
        }
        uint4 pk;
        pk.x = (unsigned)u[0] | ((unsigned)u[1] << 16);
        pk.y = (unsigned)u[2] | ((unsigned)u[3] << 16);
        pk.z = (unsigned)u[4] | ((unsigned)u[5] << 16);
        pk.w = (unsigned)u[6] | ((unsigned)u[7] << 16);
        *(uint4*)(orow + d8) = pk;
    }
    x2[g] = s;
}

// ---------------------------------------------------------------------------
// Pack codebooks -> Cbf bf16 + c2 fp32 (ascending fmaf, matches R1 c2_kernel).
// ---------------------------------------------------------------------------
__global__ __launch_bounds__(256)
void pack_c_kernel(const float* __restrict__ cb, unsigned short* __restrict__ cbf,
                   float* __restrict__ c2) {
    int g = blockIdx.x * 256 + threadIdx.x;   // n*K + k
    const float4* crow = (const float4*)(cb + (size_t)g * DD);
    unsigned short* orow = cbf + (size_t)g * DD;
    float s = 0.f;
#pragma unroll 4
    for (int i2 = 0; i2 < 16; ++i2) {
        float4 v0 = crow[2 * i2];
        float4 v1 = crow[2 * i2 + 1];
        s = fmaf(v0.x, v0.x, s); s = fmaf(v0.y, v0.y, s);
        s = fmaf(v0.z, v0.z, s); s = fmaf(v0.w, v0.w, s);
        s = fmaf(v1.x, v1.x, s); s = fmaf(v1.y, v1.y, s);
        s = fmaf(v1.z, v1.z, s); s = fmaf(v1.w, v1.w, s);
        uint4 pk;
        pk.x = (unsigned)f2bf(v0.x) | ((unsigned)f2bf(v0.y) << 16);
        pk.y = (unsigned)f2bf(v0.z) | ((unsigned)f2bf(v0.w) << 16);
        pk.z = (unsigned)f2bf(v1.x) | ((unsigned)f2bf(v1.y) << 16);
        pk.w = (unsigned)f2bf(v1.z) | ((unsigned)f2bf(v1.w) << 16);
        *(uint4*)(orow + i2 * 8) = pk;
    }
    c2[g] = s;
}

// ---------------------------------------------------------------------------
// Exact fp32 rescore of one (query m, codebook n, code k): identical
// association to the R1 passing kernel: xc = ascending-d fmaf chain,
// s = (x2 - 2*xc) + c2.  atomicMin on packed (s_bits<<32 | k) reproduces
// "min s, then lowest k" = np first-occurrence argmin (s > 0 always here).
// ---------------------------------------------------------------------------
__device__ void rescore_one(int n, int m, int k,
                            const float* __restrict__ x, const float* __restrict__ cb,
                            const float* __restrict__ x2, const float* __restrict__ c2,
                            unsigned long long* __restrict__ pmin) {
    int b = m >> 10, t = m & (TT - 1);
    const float* xp = x + ((size_t)(b * 256 + n * 128)) * TT + t;
    const float* cp = cb + ((size_t)(n * KK + k)) * DD;
    float xc = 0.f;
    for (int d = 0; d < DD; ++d)
        xc = fmaf(xp[(size_t)d * TT], cp[d], xc);
    float u = x2[n * MM + m] - 2.0f * xc;
    float s = u + c2[n * KK + k];
    unsigned long long pk = ((unsigned long long)__float_as_uint(s) << 32) | (unsigned)k;
    atomicMin(pmin + (size_t)n * MM + m, pk);
}

// ---------------------------------------------------------------------------
// Screening: grid (64 q-tiles, 2 codebooks, 4 K-splits) = 512 blocks, 512 thr.
// Block tile: 128 queries x 2048 codes, chunks of 128 codes.
// Wave tile: 32 q x 64 codes = 2x4 tiles of 16x16 MFMA; A=codes, B=queries
// (C/D: row=quad*4+reg -> code, col=lane&15 -> query).
// Phase A: exact min of y=c2-2*xc_bf per query over the split.
// Phase B: identical re-scan, collect y <= min+THR into LDS queue; rescore.
// ---------------------------------------------------------------------------
__global__ __launch_bounds__(512, 4)
void screen_kernel(const unsigned short* __restrict__ xbf,
                   const unsigned short* __restrict__ cbf,
                   const float* __restrict__ c2,
                   const float* __restrict__ x,
                   const float* __restrict__ cb32,
                   const float* __restrict__ x2,
                   unsigned long long* __restrict__ pmin) {
    __shared__ unsigned short Ash[128 * 136];   // queries, padded stride 136
    __shared__ unsigned short Bsh[128 * 136];   // code chunk, padded
    __shared__ unsigned int   minU[128];
    __shared__ float          c2s[128];
    __shared__ unsigned int   qcnt;
    __shared__ unsigned int   queue[QCAP];

    const int tid = threadIdx.x;
    const int qt  = blockIdx.x;        // 0..63
    const int n   = blockIdx.y;        // 0..1
    const int ks  = blockIdx.z;        // 0..3
    const int m0  = qt * 128;
    const int k0  = ks * 2048;

    const int wave = tid >> 6, lane = tid & 63;
    const int qw = wave >> 1, cw = wave & 1;
    const int quad = lane >> 4, l15 = lane & 15;

    // stage queries (once): rows m0..m0+127, 256 B each, into padded LDS
    {
        const unsigned short* src = xbf + ((size_t)n * MM + m0) * DD;
#pragma unroll
        for (int p = 0; p < 4; ++p) {
            int i = tid + p * 512;          // row = i>>4, 16B-seg = i&15
            int row = i >> 4, seg = i & 15;
            uint4 v = *(const uint4*)(src + (size_t)row * DD + seg * 8);
            *(uint4*)(&Ash[row * 136 + seg * 8]) = v;
        }
    }
    if (tid < 128) minU[tid] = 0xFFFFFFFFu;
    if (tid == 0)  qcnt = 0;
    __syncthreads();

    // preload query B-fragments for the whole K=128 (held in registers)
    short8 bfr[2][4];
#pragma unroll
    for (int tq = 0; tq < 2; ++tq) {
        int q = qw * 32 + tq * 16 + l15;
#pragma unroll
        for (int k4 = 0; k4 < 4; ++k4)
            bfr[tq][k4] = *(const short8*)(&Ash[q * 136 + k4 * 32 + quad * 8]);
    }

    float mloc[2] = {3.4e38f, 3.4e38f};
    float thr[2]  = {3.4e38f, 3.4e38f};

#pragma unroll
    for (int phase = 0; phase < 2; ++phase) {
        for (int ch = 0; ch < 16; ++ch) {
            __syncthreads();
            {   // stage code chunk (contiguous 32 KB global -> padded LDS)
                const unsigned short* src = cbf + ((size_t)n * KK + k0 + ch * 128) * DD;
#pragma unroll
                for (int p = 0; p < 4; ++p) {
                    int i = tid + p * 512;
                    int row = i >> 4, seg = i & 15;
                    uint4 v = *(const uint4*)(src + (size_t)row * DD + seg * 8);
                    *(uint4*)(&Bsh[row * 136 + seg * 8]) = v;
                }
                if (tid < 32)
                    *(float4*)&c2s[tid * 4] =
                        *(const float4*)(c2 + (size_t)n * KK + k0 + ch * 128 + tid * 4);
            }
            __syncthreads();

            float4v acc[4][2];
#pragma unroll
            for (int tc = 0; tc < 4; ++tc)
#pragma unroll
                for (int tq = 0; tq < 2; ++tq)
                    acc[tc][tq] = (float4v){0.f, 0.f, 0.f, 0.f};

#pragma unroll
            for (int k4 = 0; k4 < 4; ++k4) {
                short8 af[4];
#pragma unroll
                for (int tc = 0; tc < 4; ++tc) {
                    int r = cw * 64 + tc * 16 + l15;
                    af[tc] = *(const short8*)(&Bsh[r * 136 + k4 * 32 + quad * 8]);
                }
#pragma unroll
                for (int tc = 0; tc < 4; ++tc)
#pragma unroll
                    for (int tq = 0; tq < 2; ++tq)
                        acc[tc][tq] = __builtin_amdgcn_mfma_f32_16x16x32_bf16(
                            af[tc], bfr[tq][k4], acc[tc][tq], 0, 0, 0);
            }

            // epilogue: y = c2 - 2*xc (x2 is query-constant, irrelevant to argmin)
#pragma unroll
            for (int tc = 0; tc < 4; ++tc) {
                float4v c2r = *(const float4v*)(&c2s[cw * 64 + tc * 16 + quad * 4]);
#pragma unroll
                for (int tq = 0; tq < 2; ++tq) {
#pragma unroll
                    for (int rg = 0; rg < 4; ++rg) {
                        float y = fmaf(-2.0f, acc[tc][tq][rg], c2r[rg]);
                        if (phase == 0) {
                            mloc[tq] = fminf(mloc[tq], y);
                        } else if (y <= thr[tq]) {
                            unsigned idx  = atomicAdd(&qcnt, 1u);
                            unsigned code = (unsigned)(ch * 128 + cw * 64 + tc * 16 + quad * 4 + rg);
                            unsigned q    = (unsigned)(qw * 32 + tq * 16 + l15);
                            if (idx < QCAP) queue[idx] = (q << 11) | code;
                            else rescore_one(n, m0 + (int)q, k0 + (int)code,
                                             x, cb32, x2, c2, pmin);
                        }
                    }
                }
            }
        }

        if (phase == 0) {
            // merge per-query mins: shuffle across quads, then LDS atomicMin
#pragma unroll
            for (int tq = 0; tq < 2; ++tq) {
                float v = mloc[tq];
                v = fminf(v, __shfl_xor(v, 16, 64));
                v = fminf(v, __shfl_xor(v, 32, 64));
                if (quad == 0) {
                    unsigned u  = __float_as_uint(v);
                    unsigned mu = (u & 0x80000000u) ? ~u : (u | 0x80000000u);
                    atomicMin(&minU[qw * 32 + tq * 16 + l15], mu);
                }
            }
            __syncthreads();
#pragma unroll
            for (int tq = 0; tq < 2; ++tq) {
                unsigned mu = minU[qw * 32 + tq * 16 + l15];
                unsigned u  = (mu & 0x80000000u) ? (mu & 0x7FFFFFFFu) : ~mu;
                thr[tq] = __uint_as_float(u) + THR;
            }
        }
    }

    __syncthreads();
    // drain candidate queue: exact fp32 rescore
    unsigned total = qcnt; if (total > QCAP) total = QCAP;
    for (unsigned i = tid; i < total; i += 512) {
        unsigned ent = queue[i];
        rescore_one(n, m0 + (int)(ent >> 11), k0 + (int)(ent & 2047u),
                    x, cb32, x2, c2, pmin);
    }
}

// ---------------------------------------------------------------------------
// Gather quantized rows + indices + commitment loss (R1 kernel, idx source
// swapped to the packed argmin buffer).
// ---------------------------------------------------------------------------
__global__ __launch_bounds__(256)
void gather_kernel(const float* __restrict__ x, const float* __restrict__ cb,
                   const unsigned long long* __restrict__ pmin,
                   float* __restrict__ out) {
    int g  = blockIdx.x * 256 + threadIdx.x;  // 0..16383
    int t  = g & (TT - 1);
    int nn = (g >> 10) & (NCBN - 1);
    int b  = g >> 11;

    int k = (int)(pmin[(size_t)nn * MM + b * TT + t] & 0xFFFFFFFFull);
    out[OUT_IDX_OFF + (b * NCBN + nn) * TT + t] = (float)k;

    const float* crow  = cb + ((size_t)nn * KK + k) * DD;
    const float* xbase = x   + ((size_t)(b * 256 + nn * 128)) * TT + t;
    float*       obase = out + ((size_t)(b * 256 + nn * 128)) * TT + t;

    float lsum = 0.f;
#pragma unroll 4
    for (int d = 0; d < DD; d += 4) {
        float4 q = *(const float4*)(crow + d);
        float qv[4] = {q.x, q.y, q.z, q.w};
#pragma unroll
        for (int u = 0; u < 4; ++u) {
            size_t off = (size_t)(d + u) * TT;
            float xv = xbase[off];
            obase[off] = qv[u];
            float df = xv - qv[u];
            lsum = fmaf(df, df, lsum);
        }
    }

#pragma unroll
    for (int o = 32; o > 0; o >>= 1) lsum += __shfl_down(lsum, o, 64);
    __shared__ float wsum[4];
    int lane = threadIdx.x & 63, w = threadIdx.x >> 6;
    if (lane == 0) wsum[w] = lsum;
    __syncthreads();
    if (threadIdx.x == 0) {
        float tot = wsum[0] + wsum[1] + wsum[2] + wsum[3];
        atomicAdd(out + OUT_LOSS_OFF, tot * 2.384185791015625e-7f);  // 2^-22
    }
}

// ---------------------------------------------------------------------------
extern "C" void kernel_launch(void* const* d_in, const int* in_sizes, int n_in,
                              void* d_out, int out_size, void* d_ws, size_t ws_size,
                              hipStream_t stream) {
    (void)in_sizes; (void)n_in; (void)out_size; (void)ws_size;
    const float* x  = (const float*)d_in[0];
    const float* cb = (const float*)d_in[1];
    float* out = (float*)d_out;

    char* ws = (char*)d_ws;
    unsigned short* xbf = (unsigned short*)(ws);                       // 4 MiB
    unsigned short* cbf = (unsigned short*)(ws + (4u << 20));          // 4 MiB
    float* x2 = (float*)(ws + (8u << 20));                             // 64 KiB
    float* c2 = (float*)(ws + (8u << 20) + (64u << 10));               // 64 KiB
    unsigned long long* pmin =
        (unsigned long long*)(ws + (8u << 20) + (128u << 10));         // 128 KiB

    pack_x_kernel<<<dim3(64), 256, 0, stream>>>(x, xbf, x2);
    pack_c_kernel<<<dim3(64), 256, 0, stream>>>(cb, cbf, c2);
    hipMemsetAsync(pmin, 0xFF, (size_t)NCBN * MM * 8, stream);
    hipMemsetAsync((char*)d_out + (size_t)OUT_LOSS_OFF * 4, 0, 4, stream);

    screen_kernel<<<dim3(64, 2, 4), 512, 0, stream>>>(xbf, cbf, c2, x, cb, x2, pmin);
    gather_kernel<<<dim3(64), 256, 0, stream>>>(x, cb, pmin, out);
}